// Round 1
// baseline (204.084 us; speedup 1.0000x reference)
//
#include <hip/hip_runtime.h>
#include <math.h>

// VolumetricCELoss: loss = mean_{b,j}( -0.01 * log( softmax(vol[b,j])[idx(b,j)] + 1e-6 ) )
// Only needs per-slice max, sum-exp, and one gathered logit -> single streaming pass.

#define NVOX    64
#define NSLICE  136                    // B*J = 8*17
#define SLICE_N (NVOX * NVOX * NVOX)   // 262144
#define CHUNKS  16
#define CHUNK_N (SLICE_N / CHUNKS)     // 16384 floats per block
#define THREADS 256
#define PER_THREAD (CHUNK_N / THREADS / 4)  // 16 float4 per thread

__global__ __launch_bounds__(THREADS)
void vce_partial(const float* __restrict__ vol, float2* __restrict__ ws) {
    const int slice = blockIdx.x / CHUNKS;
    const int chunk = blockIdx.x % CHUNKS;
    const float4* __restrict__ p = reinterpret_cast<const float4*>(
        vol + (size_t)slice * SLICE_N + (size_t)chunk * CHUNK_N);
    const int tid = threadIdx.x;

    float m = -INFINITY;
    float s = 0.0f;

    #pragma unroll
    for (int it = 0; it < PER_THREAD; ++it) {
        float4 v = p[it * THREADS + tid];            // coalesced: 16B/lane
        // max of the 4 new values
        float m4 = fmaxf(fmaxf(v.x, v.y), fmaxf(v.z, v.w));
        float nm = fmaxf(m, m4);
        // rescale old sum once, add 4 exps
        s = s * __expf(m - nm)
          + __expf(v.x - nm) + __expf(v.y - nm)
          + __expf(v.z - nm) + __expf(v.w - nm);
        m = nm;
    }

    // block reduction of (m, s) pairs
    __shared__ float sm_m[THREADS];
    __shared__ float sm_s[THREADS];
    sm_m[tid] = m;
    sm_s[tid] = s;
    __syncthreads();
    for (int str = THREADS / 2; str > 0; str >>= 1) {
        if (tid < str) {
            float m2 = sm_m[tid + str];
            float s2 = sm_s[tid + str];
            float M  = fmaxf(m, m2);
            s = s * __expf(m - M) + s2 * __expf(m2 - M);
            m = M;
            sm_m[tid] = m;
            sm_s[tid] = s;
        }
        __syncthreads();
    }
    if (tid == 0) {
        ws[blockIdx.x] = make_float2(m, s);
    }
}

__global__ __launch_bounds__(THREADS)
void vce_final(const float* __restrict__ vol,
               const float* __restrict__ label,
               const float* __restrict__ bc,
               const float2* __restrict__ ws,
               float* __restrict__ out) {
    const int tid = threadIdx.x;
    float c = 0.0f;

    if (tid < NSLICE) {
        const int b = tid / 17;
        const int j = tid % 17;

        // merge the 16 chunk partials for this slice
        float m = -INFINITY;
        float s = 0.0f;
        #pragma unroll
        for (int i = 0; i < CHUNKS; ++i) {
            float2 pr = ws[tid * CHUNKS + i];
            float M = fmaxf(m, pr.x);
            s = s * __expf(m - M) + pr.y * __expf(pr.x - M);
            m = M;
        }

        // compute flat voxel index exactly as the reference does (fp32 op order)
        int id3[3];
        #pragma unroll
        for (int d = 0; d < 3; ++d) {
            float lab = label[(b * 17 + j) * 3 + d];
            float cen = bc[b * 3 + d];
            float norm = (lab - cen) / 1000.0f;           // BOX_RANGE
            float t = (norm + 1.0f) / 2.0f * 63.0f;       // (NVOX-1)
            int id = (int)floorf(t);
            id = min(max(id, 0), NVOX - 1);
            id3[d] = id;
        }
        const int fidx = (id3[0] * NVOX + id3[1]) * NVOX + id3[2];

        const float x = vol[(size_t)tid * SLICE_N + fidx];
        const float picked = __expf(x - m) / s;
        c = -0.01f * logf(picked + 1e-6f);                // BETA * -log(p + EPS)
    }

    __shared__ float sm[THREADS];
    sm[tid] = c;
    __syncthreads();
    for (int str = THREADS / 2; str > 0; str >>= 1) {
        if (tid < str) sm[tid] += sm[tid + str];
        __syncthreads();
    }
    if (tid == 0) out[0] = sm[0] * (1.0f / (float)NSLICE);
}

extern "C" void kernel_launch(void* const* d_in, const int* in_sizes, int n_in,
                              void* d_out, int out_size, void* d_ws, size_t ws_size,
                              hipStream_t stream) {
    const float* vol   = (const float*)d_in[0];   // volumes_batch_pred [8,17,64,64,64] f32
    const float* label = (const float*)d_in[1];   // [8,17,3] f32
    const float* bc    = (const float*)d_in[2];   // [8,3] f32
    float* out = (float*)d_out;                   // scalar f32
    float2* ws = (float2*)d_ws;                   // NSLICE*CHUNKS float2 = 17 KiB

    vce_partial<<<NSLICE * CHUNKS, THREADS, 0, stream>>>(vol, ws);
    vce_final<<<1, THREADS, 0, stream>>>(vol, label, bc, ws, out);
}

// Round 3
// 201.995 us; speedup vs baseline: 1.0103x; 1.0103x over previous
//
#include <hip/hip_runtime.h>
#include <math.h>

// VolumetricCELoss: loss = mean_{b,j}( -0.01 * log( softmax(vol[b,j])[idx(b,j)] + 1e-6 ) )
// Only per-slice (max, sum-exp) + one gathered logit are needed -> single streaming pass.

#define NVOX    64
#define NSLICE  136                    // B*J = 8*17
#define SLICE_N (NVOX * NVOX * NVOX)   // 262144
#define CHUNKS  16
#define CHUNK_N (SLICE_N / CHUNKS)     // 16384 floats per block
#define THREADS 256
#define GROUPS  4                      // 4 groups x 4 float4 = 16 float4/thread

__device__ __forceinline__ float max4(float4 v) {
    return fmaxf(fmaxf(v.x, v.y), fmaxf(v.z, v.w));
}

__global__ __launch_bounds__(THREADS)
void vce_partial(const float* __restrict__ vol, float2* __restrict__ ws) {
    const int slice = blockIdx.x / CHUNKS;
    const int chunk = blockIdx.x % CHUNKS;
    const float4* __restrict__ p = reinterpret_cast<const float4*>(
        vol + (size_t)slice * SLICE_N + (size_t)chunk * CHUNK_N);
    const int tid = threadIdx.x;

    float m = -INFINITY;
    float s = 0.0f;

    // 16-element groups: independent exps within a group, only 1 rescale-exp
    // per group -> serial exp chain is 4 deep instead of 16.
    #pragma unroll
    for (int g = 0; g < GROUPS; ++g) {
        float4 v0 = p[(g * 4 + 0) * THREADS + tid];
        float4 v1 = p[(g * 4 + 1) * THREADS + tid];
        float4 v2 = p[(g * 4 + 2) * THREADS + tid];
        float4 v3 = p[(g * 4 + 3) * THREADS + tid];

        float gm = fmaxf(fmaxf(max4(v0), max4(v1)), fmaxf(max4(v2), max4(v3)));
        float nm = fmaxf(m, gm);

        float sg;
        sg  = __expf(v0.x - nm) + __expf(v0.y - nm) + __expf(v0.z - nm) + __expf(v0.w - nm);
        sg += __expf(v1.x - nm) + __expf(v1.y - nm) + __expf(v1.z - nm) + __expf(v1.w - nm);
        sg += __expf(v2.x - nm) + __expf(v2.y - nm) + __expf(v2.z - nm) + __expf(v2.w - nm);
        sg += __expf(v3.x - nm) + __expf(v3.y - nm) + __expf(v3.z - nm) + __expf(v3.w - nm);

        s = s * __expf(m - nm) + sg;
        m = nm;
    }

    // wave-level (64-lane) reduction of (m, s), then cross-wave via LDS
    #pragma unroll
    for (int d = 1; d < 64; d <<= 1) {
        float m2 = __shfl_xor(m, d, 64);
        float s2 = __shfl_xor(s, d, 64);
        float M  = fmaxf(m, m2);
        s = s * __expf(m - M) + s2 * __expf(m2 - M);
        m = M;
    }

    __shared__ float sm_m[4];
    __shared__ float sm_s[4];
    const int wave = tid >> 6;
    if ((tid & 63) == 0) { sm_m[wave] = m; sm_s[wave] = s; }
    __syncthreads();
    if (tid == 0) {
        float M = sm_m[0], S = sm_s[0];
        #pragma unroll
        for (int w = 1; w < 4; ++w) {
            float m2 = sm_m[w], s2 = sm_s[w];
            float nm = fmaxf(M, m2);
            S = S * __expf(M - nm) + s2 * __expf(m2 - nm);
            M = nm;
        }
        ws[blockIdx.x] = make_float2(M, S);
    }
}

__global__ __launch_bounds__(THREADS)
void vce_final(const float* __restrict__ vol,
               const float* __restrict__ label,
               const float* __restrict__ bc,
               const float2* __restrict__ ws,
               float* __restrict__ out) {
    const int tid = threadIdx.x;
    float c = 0.0f;

    if (tid < NSLICE) {
        const int b = tid / 17;
        const int j = tid % 17;

        float m = -INFINITY;
        float s = 0.0f;
        #pragma unroll
        for (int i = 0; i < CHUNKS; ++i) {
            float2 pr = ws[tid * CHUNKS + i];
            float M = fmaxf(m, pr.x);
            s = s * __expf(m - M) + pr.y * __expf(pr.x - M);
            m = M;
        }

        // flat voxel index, fp32 op order identical to the reference
        int id3[3];
        #pragma unroll
        for (int d = 0; d < 3; ++d) {
            float lab = label[(b * 17 + j) * 3 + d];
            float cen = bc[b * 3 + d];
            float norm = (lab - cen) / 1000.0f;           // BOX_RANGE
            float t = (norm + 1.0f) / 2.0f * 63.0f;       // (NVOX-1)
            int id = (int)floorf(t);
            id = min(max(id, 0), NVOX - 1);
            id3[d] = id;
        }
        const int fidx = (id3[0] * NVOX + id3[1]) * NVOX + id3[2];

        const float x = vol[(size_t)tid * SLICE_N + fidx];
        const float picked = __expf(x - m) / s;
        c = -0.01f * logf(picked + 1e-6f);                // BETA * -log(p + EPS)
    }

    __shared__ float sm[THREADS];
    sm[tid] = c;
    __syncthreads();
    for (int str = THREADS / 2; str > 0; str >>= 1) {
        if (tid < str) sm[tid] += sm[tid + str];
        __syncthreads();
    }
    if (tid == 0) out[0] = sm[0] * (1.0f / (float)NSLICE);
}

extern "C" void kernel_launch(void* const* d_in, const int* in_sizes, int n_in,
                              void* d_out, int out_size, void* d_ws, size_t ws_size,
                              hipStream_t stream) {
    const float* vol   = (const float*)d_in[0];   // volumes_batch_pred [8,17,64,64,64] f32
    const float* label = (const float*)d_in[1];   // [8,17,3] f32
    const float* bc    = (const float*)d_in[2];   // [8,3] f32
    float* out = (float*)d_out;                   // scalar f32
    float2* ws = (float2*)d_ws;                   // NSLICE*CHUNKS float2 = 17 KiB

    vce_partial<<<NSLICE * CHUNKS, THREADS, 0, stream>>>(vol, ws);
    vce_final<<<1, THREADS, 0, stream>>>(vol, label, bc, ws, out);
}